// Round 1
// 624.087 us; speedup vs baseline: 1.2658x; 1.2658x over previous
//
#include <hip/hip_runtime.h>
#include <hip/hip_bf16.h>
#include <math.h>

#define TPB 256

constexpr int   B_  = 256;
constexpr int   C_  = 1024;
constexpr int   N_  = 80;
constexpr int   BNr = B_ * N_;                 // 20480 rows for BN / GEMM M
constexpr int   CN  = C_ * N_;                 // 81920
constexpr long  BCN = (long)B_ * C_ * N_;      // 20971520
constexpr int   NN  = N_ * N_;                 // 6400
constexpr int   BNN = B_ * NN;                 // 1638400
constexpr float EPSf = 1e-5f;

typedef __bf16 bf16x8 __attribute__((ext_vector_type(8)));
typedef float  f32x4  __attribute__((ext_vector_type(4)));

__device__ __forceinline__ float leakyf(float v) { return v >= 0.0f ? v : 0.2f * v; }

__device__ __forceinline__ ushort f2bf(float f) {
  __hip_bfloat16 h = __float2bfloat16(f);
  ushort u; __builtin_memcpy(&u, &h, 2); return u;
}
__device__ __forceinline__ float b2f(ushort u) {
  __hip_bfloat16 h; __builtin_memcpy(&h, &u, 2);
  return __bfloat162float(h);
}

#define GLOBAL_AS __attribute__((address_space(1)))
#define LDS_AS    __attribute__((address_space(3)))
__device__ __forceinline__ void load_lds16(const void* g, void* l) {
  __builtin_amdgcn_global_load_lds((const GLOBAL_AS void*)g, (LDS_AS void*)l, 16, 0, 0);
}

// ---------------------------------------------------------------------------
// K0: sadj = minmax(adj_param); D = rsqrt(rowsum);
// adj_bf[n*96+m] = bf16(D[n]*sadj[m,n]*D[m]) for m<80, 0 for m in [80,96).
// ---------------------------------------------------------------------------
__global__ void k_prep_adj(const float* __restrict__ ap, float* __restrict__ sadj,
                           ushort* __restrict__ adj_bf, float* __restrict__ lossa) {
  __shared__ float s[NN];
  __shared__ float red[TPB];
  __shared__ float s_lo, s_hi;
  __shared__ float sD[N_];
  const int t = threadIdx.x;
  float lo = 3.4e38f, hi = -3.4e38f;
  for (int i = t; i < NN; i += TPB) { float v = ap[i]; s[i] = v; lo = fminf(lo, v); hi = fmaxf(hi, v); }
  red[t] = lo; __syncthreads();
  for (int o = 128; o > 0; o >>= 1) { if (t < o) red[t] = fminf(red[t], red[t + o]); __syncthreads(); }
  if (t == 0) s_lo = red[0];
  __syncthreads();
  red[t] = hi; __syncthreads();
  for (int o = 128; o > 0; o >>= 1) { if (t < o) red[t] = fmaxf(red[t], red[t + o]); __syncthreads(); }
  if (t == 0) s_hi = red[0];
  __syncthreads();
  const float inv = 1.0f / (s_hi - s_lo);
  for (int i = t; i < NN; i += TPB) { float v = (s[i] - s_lo) * inv; s[i] = v; sadj[i] = v; }
  __syncthreads();
  if (t < N_) { float sum = 0.f; for (int m = 0; m < N_; ++m) sum += s[t * N_ + m]; sD[t] = rsqrtf(sum); }
  if (t == 0) *lossa = 0.0f;
  __syncthreads();
  for (int i = t; i < N_ * 96; i += TPB) {
    const int n = i / 96, m = i % 96;
    adj_bf[i] = f2bf((m < N_) ? sD[n] * s[m * N_ + n] * sD[m] : 0.0f);
  }
}

// ---------------------------------------------------------------------------
// KW: Wt[o][c] = bf16(W[c][o]) — transpose + convert, 32x32 LDS tiles.
// ---------------------------------------------------------------------------
__global__ void k_w_bf_t(const float* __restrict__ W, ushort* __restrict__ Wt) {
  __shared__ float s[32][33];
  const int t = threadIdx.x;
  const int tx = t % 32, ty = t / 32;            // 8 rows per pass
  const int r0 = blockIdx.y * 32, c0 = blockIdx.x * 32;
#pragma unroll
  for (int k = 0; k < 4; ++k) s[ty + 8 * k][tx] = W[(size_t)(r0 + ty + 8 * k) * C_ + c0 + tx];
  __syncthreads();
#pragma unroll
  for (int k = 0; k < 4; ++k) Wt[(size_t)(c0 + ty + 8 * k) * C_ + r0 + tx] = f2bf(s[tx][ty + 8 * k]);
}

// ---------------------------------------------------------------------------
// KW2: split Wco (80 x 2048) into two bf16 (80 x 1024) K-major buffers.
// ---------------------------------------------------------------------------
__global__ void k_wco_bf(const float* __restrict__ Wco, ushort* __restrict__ Wco1t,
                         ushort* __restrict__ Wco2t) {
  const int i4 = (blockIdx.x * TPB + threadIdx.x) * 4;   // 80*2048 elems
  const int o = i4 >> 11, k = i4 & 2047;
  float4 v = *(const float4*)&Wco[(size_t)o * 2048 + k];
  ushort4 u;
  u.x = f2bf(v.x); u.y = f2bf(v.y); u.z = f2bf(v.z); u.w = f2bf(v.w);
  if (k < C_) *(ushort4*)&Wco1t[(size_t)o * C_ + k] = u;
  else        *(ushort4*)&Wco2t[(size_t)o * C_ + (k - C_)] = u;
}

// ---------------------------------------------------------------------------
// KW3: plain fp32 -> bf16 elementwise convert (for Wg, already o-major/K-contig).
// ---------------------------------------------------------------------------
__global__ void k_cvt_bf(const float* __restrict__ W, ushort* __restrict__ Wb) {
  const long i4 = ((long)blockIdx.x * TPB + threadIdx.x) * 4;
  float4 v = *(const float4*)&W[i4];
  ushort4 u;
  u.x = f2bf(v.x); u.y = f2bf(v.y); u.z = f2bf(v.z); u.w = f2bf(v.w);
  *(ushort4*)&Wb[i4] = u;
}

// K-zero: go accumulator (20480 floats).
__global__ void k_zero_go(float* __restrict__ go) {
  const int i = (blockIdx.x * TPB + threadIdx.x) * 4;
  float4 z = make_float4(0.f, 0.f, 0.f, 0.f);
  *(float4*)&go[i] = z;
}

// ---------------------------------------------------------------------------
// K1v3: MFMA fold.  out[(b*80+n)*1024 + c] (bf16, B,N,C) =
//   sum_m adj[n,m] * X[b, c, m]       (X fp32 in B,C,N layout)
// mode 0: adjsrc = adj_bf global (80x96 bf16, prepadded).
// mode 1: adjsrc = dadj fp32 (B,80,80); tadj computed per block in LDS.
// ---------------------------------------------------------------------------
__global__ __launch_bounds__(256) void k_fold_mfma(const float* __restrict__ X,
                                                   const void* __restrict__ adjsrc,
                                                   ushort* __restrict__ outp, int mode) {
  __shared__ __align__(16) ushort sX[128][104];     // rows c, cols m (pad->104, b128 2-way free)
  __shared__ __align__(16) ushort sAdj[80][104];    // rows n, cols m
  __shared__ float sD[N_];
  const int t = threadIdx.x;
  const int b  = blockIdx.x >> 3;
  const int c0 = (blockIdx.x & 7) * 128;

  // ---- adjacency -> sAdj (bf16, m 80..95 zero) ----
  if (mode == 0) {
    const ushort* ab = (const ushort*)adjsrc;
    for (int i = t; i < (N_ * 96) / 4; i += TPB) {
      ushort4 v = *(const ushort4*)&ab[i * 4];
      *(ushort4*)&sAdj[(i * 4) / 96][(i * 4) % 96] = v;
    }
    __syncthreads();
  } else {
    float* sF = (float*)&sX[0][0];                  // 80*80 fp32 = 25.6KB <= sX
    const float* db = (const float*)adjsrc + (size_t)b * NN;
    for (int i = t; i < NN / 4; i += TPB) *(float4*)&sF[i * 4] = *(const float4*)&db[i * 4];
    __syncthreads();
    if (t < N_) { float s = 0.f; for (int m = 0; m < N_; ++m) s += sF[t * N_ + m]; sD[t] = rsqrtf(s); }
    __syncthreads();
    for (int i = t; i < N_ * 96; i += TPB) {
      const int n = i / 96, m = i % 96;
      sAdj[n][m] = f2bf((m < N_) ? sF[m * N_ + n] * sD[n] * sD[m] : 0.0f);
    }
    __syncthreads();                                 // before sX overwrite
  }

  // ---- stage X (128 rows x 80 m) fp32 -> bf16; zero pad m 80..95 ----
  const float* Xb = X + ((size_t)b * C_ + c0) * N_;
  for (int i = t; i < (128 * N_) / 4; i += TPB) {
    float4 v = *(const float4*)&Xb[i * 4];
    const int r = (i * 4) / N_, m = (i * 4) % N_;
    ushort4 u; u.x = f2bf(v.x); u.y = f2bf(v.y); u.z = f2bf(v.z); u.w = f2bf(v.w);
    *(ushort4*)&sX[r][m] = u;
  }
  for (int i = t; i < (128 * 16) / 4; i += TPB) {
    const int r = i / 4, m = 80 + (i % 4) * 4;
    ushort4 z; z.x = 0; z.y = 0; z.z = 0; z.w = 0;
    *(ushort4*)&sX[r][m] = z;
  }
  __syncthreads();

  const int lane = t & 63, wid = t >> 6;
  const int l16 = lane & 15, lq = lane >> 4;
  f32x4 acc[2][5];
#pragma unroll
  for (int i = 0; i < 2; ++i)
#pragma unroll
    for (int j = 0; j < 5; ++j) { f32x4 z = {0.f, 0.f, 0.f, 0.f}; acc[i][j] = z; }
  bf16x8 af[2][3], bfr[5][3];
#pragma unroll
  for (int i = 0; i < 2; ++i)
#pragma unroll
    for (int kk = 0; kk < 3; ++kk)
      af[i][kk] = *(const bf16x8*)&sX[wid * 32 + i * 16 + l16][kk * 32 + lq * 8];
#pragma unroll
  for (int j = 0; j < 5; ++j)
#pragma unroll
    for (int kk = 0; kk < 3; ++kk)
      bfr[j][kk] = *(const bf16x8*)&sAdj[j * 16 + l16][kk * 32 + lq * 8];
#pragma unroll
  for (int i = 0; i < 2; ++i)
#pragma unroll
    for (int j = 0; j < 5; ++j)
#pragma unroll
      for (int kk = 0; kk < 3; ++kk)
        acc[i][j] = __builtin_amdgcn_mfma_f32_16x16x32_bf16(af[i][kk], bfr[j][kk], acc[i][j], 0, 0, 0);

  // ---- epilogue: D[row=c_local (lq*4+reg)][col=n (l16)] -> (B,N,C) ushort4 ----
  ushort* ob = outp + (size_t)b * CN;
#pragma unroll
  for (int i = 0; i < 2; ++i) {
    const int c = c0 + wid * 32 + i * 16 + lq * 4;
#pragma unroll
    for (int j = 0; j < 5; ++j) {
      const int n = j * 16 + l16;
      ushort4 u;
      u.x = f2bf(acc[i][j][0]); u.y = f2bf(acc[i][j][1]);
      u.z = f2bf(acc[i][j][2]); u.w = f2bf(acc[i][j][3]);
      *(ushort4*)&ob[(size_t)n * C_ + c] = u;
    }
  }
}

// ---------------------------------------------------------------------------
// K2: MFMA GEMM. A: 20480 x 1024 bf16 row-major. Bt: 1024 x 1024 bf16 row-major.
// out[b, o, n] (B,C,N) = sum_k A[m=(b,n)][k] * Bt[o][k];  out_bf: 1 -> bf16 store.
// XCD-chunked tile swizzle: each XCD gets 20 consecutive row-panels so the
// 8 col-tiles sharing an A-panel hit the same per-XCD L2.
// ---------------------------------------------------------------------------
__global__ __launch_bounds__(256) void k_gemm_mfma(const ushort* __restrict__ A,
                                                   const ushort* __restrict__ Bt,
                                                   void* __restrict__ outp, int out_bf) {
  __shared__ ushort smA[128 * 32];
  __shared__ ushort smB[128 * 32];
  const int t = threadIdx.x;
  const int lane = t & 63, wid = t >> 6;
  // grid = (8, 160) = 1280 blocks; 1280 % 8 == 0 -> simple bijective swizzle.
  const int lin = blockIdx.y * 8 + blockIdx.x;
  const int v   = (lin & 7) * 160 + (lin >> 3);
  const int m0 = (v >> 3) * 128, o0 = (v & 7) * 128;
  const int wm = wid & 1, wn = wid >> 1;
  const int rto = t >> 2, ch = t & 3;
  const size_t gA0 = (size_t)(m0 + rto) * C_ + (size_t)ch * 8;
  const size_t gB0 = (size_t)(o0 + rto) * C_ + (size_t)ch * 8;
  ushort* ldsA = smA + wid * 512;
  ushort* ldsB = smB + wid * 512;
  const int l16 = lane & 15, lq = lane >> 4;
  const int raOff = (wm * 64 + l16) * 32 + lq * 8;
  const int rbOff = (wn * 64 + l16) * 32 + lq * 8;
  f32x4 zero = {0.f, 0.f, 0.f, 0.f};
  f32x4 acc[4][4];
#pragma unroll
  for (int i = 0; i < 4; ++i)
#pragma unroll
    for (int j = 0; j < 4; ++j) acc[i][j] = zero;
  for (int k0 = 0; k0 < C_; k0 += 32) {
    load_lds16(A  + gA0 + k0,              ldsA);
    load_lds16(A  + gA0 + 64 * C_ + k0,    ldsA + 2048);
    load_lds16(Bt + gB0 + k0,              ldsB);
    load_lds16(Bt + gB0 + 64 * C_ + k0,    ldsB + 2048);
    __syncthreads();
    bf16x8 af[4], bfr[4];
#pragma unroll
    for (int i = 0; i < 4; ++i) af[i]  = *(const bf16x8*)&smA[raOff + i * 512];
#pragma unroll
    for (int j = 0; j < 4; ++j) bfr[j] = *(const bf16x8*)&smB[rbOff + j * 512];
#pragma unroll
    for (int i = 0; i < 4; ++i)
#pragma unroll
      for (int j = 0; j < 4; ++j)
        acc[i][j] = __builtin_amdgcn_mfma_f32_16x16x32_bf16(af[i], bfr[j], acc[i][j], 0, 0, 0);
    __syncthreads();
  }
  const int og0 = o0 + wn * 64 + l16;
#pragma unroll
  for (int i = 0; i < 4; ++i) {
    const int mg = m0 + wm * 64 + i * 16 + lq * 4;
    const int b  = mg / 80;
    const int n0 = mg - b * 80;
#pragma unroll
    for (int j = 0; j < 4; ++j) {
      const int og = og0 + j * 16;
      const size_t off = (size_t)b * CN + (size_t)og * N_ + n0;
      if (out_bf) {
        ushort4 v4;
        v4.x = f2bf(acc[i][j][0]); v4.y = f2bf(acc[i][j][1]);
        v4.z = f2bf(acc[i][j][2]); v4.w = f2bf(acc[i][j][3]);
        *(ushort4*)((ushort*)outp + off) = v4;
      } else {
        *(f32x4*)((float*)outp + off) = acc[i][j];
      }
    }
  }
}

// ---------------------------------------------------------------------------
// K2b: dadj MFMA GEMM. A: x2t bf16 (M=20480, K=1024). Bw: Wco2t bf16 (80,1024).
// dadj[b,o,n] = go[b,o] + bco[o] + sum_k A[m=(b,n)][k]*Bw[o][k].
// ---------------------------------------------------------------------------
__global__ __launch_bounds__(256) void k_dadj_mfma(const ushort* __restrict__ A,
                                                   const ushort* __restrict__ Bw,
                                                   const float* __restrict__ go,
                                                   const float* __restrict__ bco,
                                                   float* __restrict__ dadj) {
  __shared__ ushort smA[128 * 32];
  __shared__ ushort smB[80 * 32];
  const int t = threadIdx.x;
  const int lane = t & 63, wid = t >> 6;
  const int m0 = blockIdx.x * 128;
  const int rto = t >> 2, ch = t & 3;
  const size_t gA0 = (size_t)(m0 + rto) * C_ + (size_t)ch * 8;
  ushort* ldsA = smA + wid * 512;
  const int l16 = lane & 15, lq = lane >> 4;
  const int wrow = wid * 32;
  f32x4 zero = {0.f, 0.f, 0.f, 0.f};
  f32x4 acc[2][5];
#pragma unroll
  for (int i = 0; i < 2; ++i)
#pragma unroll
    for (int j = 0; j < 5; ++j) acc[i][j] = zero;
  for (int k0 = 0; k0 < C_; k0 += 32) {
    load_lds16(A + gA0 + k0,            ldsA);
    load_lds16(A + gA0 + 64 * C_ + k0,  ldsA + 2048);
    {
      const int idx = t;                               // 320 chunks of 16B
      uint4 v = *(const uint4*)&Bw[(size_t)(idx >> 2) * C_ + k0 + (idx & 3) * 8];
      *(uint4*)&smB[idx * 8] = v;
      if (t < 64) {
        const int idx2 = 256 + t;
        uint4 v2 = *(const uint4*)&Bw[(size_t)(idx2 >> 2) * C_ + k0 + (idx2 & 3) * 8];
        *(uint4*)&smB[idx2 * 8] = v2;
      }
    }
    __syncthreads();
    bf16x8 af[2], bfr[5];
#pragma unroll
    for (int i = 0; i < 2; ++i) af[i]  = *(const bf16x8*)&smA[(wrow + i * 16 + l16) * 32 + lq * 8];
#pragma unroll
    for (int j = 0; j < 5; ++j) bfr[j] = *(const bf16x8*)&smB[(j * 16 + l16) * 32 + lq * 8];
#pragma unroll
    for (int i = 0; i < 2; ++i)
#pragma unroll
      for (int j = 0; j < 5; ++j)
        acc[i][j] = __builtin_amdgcn_mfma_f32_16x16x32_bf16(af[i], bfr[j], acc[i][j], 0, 0, 0);
    __syncthreads();
  }
#pragma unroll
  for (int i = 0; i < 2; ++i) {
    const int mg = m0 + wrow + i * 16 + lq * 4;
    const int b  = mg / 80;
    const int n0 = mg - b * 80;
    const float* gob = go + b * N_;
#pragma unroll
    for (int j = 0; j < 5; ++j) {
      const int o = j * 16 + l16;
      const float g = gob[o] + bco[o];
      f32x4 v = acc[i][j];
      v[0] += g; v[1] += g; v[2] += g; v[3] += g;
      *(f32x4*)&dadj[(size_t)b * NN + (size_t)o * N_ + n0] = v;
    }
  }
}

// ---------------------------------------------------------------------------
// K2c: glb1 MFMA GEMM. A: glb0_bf (256 x 1024). Bw: Wg_bf (1024 x 1024, K-contig).
// glb1[m,o] = bias[o] + sum_k A[m,k]*Bw[o,k].  64x64 tiles, BK=64 -> 64 blocks.
// ---------------------------------------------------------------------------
__global__ __launch_bounds__(256) void k_glb_mfma(const ushort* __restrict__ A,
                                                  const ushort* __restrict__ Bw,
                                                  const float* __restrict__ bias,
                                                  float* __restrict__ outp) {
  __shared__ ushort smA[2][64 * 32];
  __shared__ ushort smB[2][64 * 32];
  const int t = threadIdx.x;
  const int lane = t & 63, wid = t >> 6;
  const int o0 = blockIdx.x * 64, m0 = blockIdx.y * 64;
  const int rto = t >> 2, ch = t & 3;
  const size_t gA0 = (size_t)(m0 + rto) * C_ + (size_t)ch * 8;
  const size_t gB0 = (size_t)(o0 + rto) * C_ + (size_t)ch * 8;
  const int l16 = lane & 15, lq = lane >> 4;
  const int wm = wid & 1, wn = wid >> 1;
  f32x4 zero = {0.f, 0.f, 0.f, 0.f};
  f32x4 acc[2][2];
#pragma unroll
  for (int i = 0; i < 2; ++i)
#pragma unroll
    for (int j = 0; j < 2; ++j) acc[i][j] = zero;
  for (int k0 = 0; k0 < C_; k0 += 64) {
    load_lds16(A  + gA0 + k0,       smA[0] + wid * 512);
    load_lds16(A  + gA0 + k0 + 32,  smA[1] + wid * 512);
    load_lds16(Bw + gB0 + k0,       smB[0] + wid * 512);
    load_lds16(Bw + gB0 + k0 + 32,  smB[1] + wid * 512);
    __syncthreads();
#pragma unroll
    for (int h = 0; h < 2; ++h) {
      bf16x8 af[2], bfr[2];
#pragma unroll
      for (int i = 0; i < 2; ++i) af[i]  = *(const bf16x8*)&smA[h][(wm * 32 + i * 16 + l16) * 32 + lq * 8];
#pragma unroll
      for (int j = 0; j < 2; ++j) bfr[j] = *(const bf16x8*)&smB[h][(wn * 32 + j * 16 + l16) * 32 + lq * 8];
#pragma unroll
      for (int i = 0; i < 2; ++i)
#pragma unroll
        for (int j = 0; j < 2; ++j)
          acc[i][j] = __builtin_amdgcn_mfma_f32_16x16x32_bf16(af[i], bfr[j], acc[i][j], 0, 0, 0);
    }
    __syncthreads();
  }
#pragma unroll
  for (int i = 0; i < 2; ++i) {
    const int mg = m0 + wm * 32 + i * 16 + lq * 4;
#pragma unroll
    for (int j = 0; j < 2; ++j) {
      const int og = o0 + wn * 32 + j * 16 + l16;
      const float bs = bias[og];
      f32x4 v = acc[i][j];
#pragma unroll
      for (int r = 0; r < 4; ++r) outp[(size_t)(mg + r) * C_ + og] = v[r] + bs;
    }
  }
}

// ---------------------------------------------------------------------------
// K2d: go MFMA GEMM, split-K x8.  A: glbf_bf (256 x 1024). Bw: Wco1t (80 x 1024).
// go[m,o] += sum_{k in chunk} A[m,k]*Bw[o,k]  (go pre-zeroed; bias in k_dadj).
// grid (8 k-chunks, 2 m-tiles) = 16 blocks, 4 K-iters each.
// ---------------------------------------------------------------------------
__global__ __launch_bounds__(256) void k_go_mfma(const ushort* __restrict__ A,
                                                 const ushort* __restrict__ Bw,
                                                 float* __restrict__ go) {
  __shared__ ushort smA[128 * 32];
  __shared__ ushort smB[80 * 32];
  const int t = threadIdx.x;
  const int lane = t & 63, wid = t >> 6;
  const int kbase = blockIdx.x * 128;
  const int m0 = blockIdx.y * 128;
  const int rto = t >> 2, ch = t & 3;
  const size_t gA0 = (size_t)(m0 + rto) * C_ + (size_t)ch * 8;
  ushort* ldsA = smA + wid * 512;
  const int l16 = lane & 15, lq = lane >> 4;
  const int wrow = wid * 32;
  f32x4 zero = {0.f, 0.f, 0.f, 0.f};
  f32x4 acc[2][5];
#pragma unroll
  for (int i = 0; i < 2; ++i)
#pragma unroll
    for (int j = 0; j < 5; ++j) acc[i][j] = zero;
  for (int kk0 = 0; kk0 < 128; kk0 += 32) {
    const int k0 = kbase + kk0;
    load_lds16(A + gA0 + k0,            ldsA);
    load_lds16(A + gA0 + 64 * C_ + k0,  ldsA + 2048);
    {
      const int idx = t;
      uint4 v = *(const uint4*)&Bw[(size_t)(idx >> 2) * C_ + k0 + (idx & 3) * 8];
      *(uint4*)&smB[idx * 8] = v;
      if (t < 64) {
        const int idx2 = 256 + t;
        uint4 v2 = *(const uint4*)&Bw[(size_t)(idx2 >> 2) * C_ + k0 + (idx2 & 3) * 8];
        *(uint4*)&smB[idx2 * 8] = v2;
      }
    }
    __syncthreads();
    bf16x8 af[2], bfr[5];
#pragma unroll
    for (int i = 0; i < 2; ++i) af[i]  = *(const bf16x8*)&smA[(wrow + i * 16 + l16) * 32 + lq * 8];
#pragma unroll
    for (int j = 0; j < 5; ++j) bfr[j] = *(const bf16x8*)&smB[(j * 16 + l16) * 32 + lq * 8];
#pragma unroll
    for (int i = 0; i < 2; ++i)
#pragma unroll
      for (int j = 0; j < 5; ++j)
        acc[i][j] = __builtin_amdgcn_mfma_f32_16x16x32_bf16(af[i], bfr[j], acc[i][j], 0, 0, 0);
    __syncthreads();
  }
#pragma unroll
  for (int i = 0; i < 2; ++i) {
    const int mg = m0 + wrow + i * 16 + lq * 4;
#pragma unroll
    for (int j = 0; j < 5; ++j) {
      const int o = j * 16 + l16;
#pragma unroll
      for (int r = 0; r < 4; ++r)
        atomicAdd(&go[(size_t)(mg + r) * N_ + o], acc[i][j][r]);
    }
  }
}

// ---------------------------------------------------------------------------
// K3: BN stats per channel over (b,n) — fp32 (B,C,N) input, float4 loads.
// ---------------------------------------------------------------------------
__global__ void k_bn_stats(const float* __restrict__ X, float* __restrict__ mu, float* __restrict__ rstd) {
  const int c = blockIdx.x, t = threadIdx.x;
  const float* base = X + (long)c * N_;
  float s = 0.f, sq = 0.f;
  for (int i4 = t; i4 < BNr / 4; i4 += TPB) {
    const int b = i4 / 20, n0 = (i4 % 20) * 4;
    float4 v = *(const float4*)&base[(long)b * CN + n0];
    s += v.x + v.y + v.z + v.w;
    sq += v.x * v.x + v.y * v.y + v.z * v.z + v.w * v.w;
  }
  __shared__ float rs[TPB], rq[TPB];
  rs[t] = s; rq[t] = sq; __syncthreads();
  for (int o = 128; o > 0; o >>= 1) { if (t < o) { rs[t] += rs[t + o]; rq[t] += rq[t + o]; } __syncthreads(); }
  if (t == 0) {
    const float m = rs[0] / BNr;
    const float var = rq[0] / BNr - m * m;
    mu[c] = m;
    rstd[c] = rsqrtf(var + EPSf);
  }
}

// K3b: same, bf16 (B,C,N) input.
__global__ void k_bn_stats_bf(const ushort* __restrict__ X, float* __restrict__ mu, float* __restrict__ rstd) {
  const int c = blockIdx.x, t = threadIdx.x;
  const ushort* base = X + (long)c * N_;
  float s = 0.f, sq = 0.f;
  for (int i4 = t; i4 < BNr / 4; i4 += TPB) {
    const int b = i4 / 20, n0 = (i4 % 20) * 4;
    ushort4 v = *(const ushort4*)&base[(long)b * CN + n0];
    const float f0 = b2f(v.x), f1 = b2f(v.y), f2 = b2f(v.z), f3 = b2f(v.w);
    s += f0 + f1 + f2 + f3;
    sq += f0 * f0 + f1 * f1 + f2 * f2 + f3 * f3;
  }
  __shared__ float rs[TPB], rq[TPB];
  rs[t] = s; rq[t] = sq; __syncthreads();
  for (int o = 128; o > 0; o >>= 1) { if (t < o) { rs[t] += rs[t + o]; rq[t] += rq[t + o]; } __syncthreads(); }
  if (t == 0) {
    const float m = rs[0] / BNr;
    const float var = rq[0] / BNr - m * m;
    mu[c] = m;
    rstd[c] = rsqrtf(var + EPSf);
  }
}

// ---------------------------------------------------------------------------
// K4: x2 = x + leaky(bn(hT_bf16)) elementwise in (B,C,N).
// ---------------------------------------------------------------------------
__global__ void k_x2(const float* __restrict__ x, const ushort* __restrict__ hT,
                     const float* __restrict__ g, const float* __restrict__ be,
                     const float* __restrict__ mu, const float* __restrict__ rstd,
                     float* __restrict__ x2) {
  const long i = ((long)blockIdx.x * TPB + threadIdx.x) * 4;
  const int c = (int)((i / N_) % C_);
  ushort4 hu = *(const ushort4*)&hT[i];
  const float4 xv = *(const float4*)&x[i];
  const float gm = g[c] * rstd[c], m = mu[c], bb = be[c];
  float4 o;
  o.x = xv.x + leakyf(gm * (b2f(hu.x) - m) + bb);
  o.y = xv.y + leakyf(gm * (b2f(hu.y) - m) + bb);
  o.z = xv.z + leakyf(gm * (b2f(hu.z) - m) + bb);
  o.w = xv.w + leakyf(gm * (b2f(hu.w) - m) + bb);
  *(float4*)&x2[i] = o;
}

// ---------------------------------------------------------------------------
// K4b: x2t[b,n,c] = bf16(x2[b,c,n]) — transpose to MFMA A layout.
// ---------------------------------------------------------------------------
__global__ __launch_bounds__(256) void k_x2t(const float* __restrict__ x2, ushort* __restrict__ x2t) {
  __shared__ float s[64][84];
  const int t = threadIdx.x;
  const long row0 = (long)blockIdx.x * 64;
  const int b = (int)(row0 >> 10), c0 = (int)(row0 & 1023);
  const float* Ab = x2 + row0 * N_;
  for (int i4 = t; i4 < (64 * N_) / 4; i4 += TPB) {
    float4 v = *(const float4*)&Ab[i4 * 4];
    *(float4*)&s[(i4 * 4) / N_][(i4 * 4) % N_] = v;
  }
  __syncthreads();
  const int tx = t % 16, ty = t / 16;
  ushort* ob = x2t + (size_t)b * CN + c0 + tx * 4;
#pragma unroll
  for (int u = 0; u < 5; ++u) {
    const int n = ty + 16 * u;
    ushort4 v;
    v.x = f2bf(s[tx * 4 + 0][n]); v.y = f2bf(s[tx * 4 + 1][n]);
    v.z = f2bf(s[tx * 4 + 2][n]); v.w = f2bf(s[tx * 4 + 3][n]);
    *(ushort4*)&ob[(size_t)n * C_] = v;
  }
}

// ---------------------------------------------------------------------------
// K5: glb0_bf[b,c] = bf16(mean over n of x2[b,c,:]). One wave per row.
// ---------------------------------------------------------------------------
__global__ void k_glb0(const float* __restrict__ x2, ushort* __restrict__ glb0b) {
  const int gid = blockIdx.x * TPB + threadIdx.x;
  const int wave = gid >> 6, lane = gid & 63;
  const float* r = x2 + (long)wave * N_;
  float v = r[lane];
  if (lane < 16) v += r[64 + lane];
#pragma unroll
  for (int o = 32; o > 0; o >>= 1) v += __shfl_down(v, o);
  if (lane == 0) glb0b[wave] = f2bf(v * (1.0f / N_));
}

// ---------------------------------------------------------------------------
// K7: BN over batch (256 rows) per channel + leaky -> bf16 out.
// ---------------------------------------------------------------------------
__global__ void k_bng(const float* __restrict__ glb1, const float* __restrict__ gg,
                      const float* __restrict__ gb, ushort* __restrict__ glbf) {
  const int c = blockIdx.x, t = threadIdx.x;
  const float v = glb1[(long)t * C_ + c];
  __shared__ float rs[TPB], rq[TPB];
  rs[t] = v; rq[t] = v * v; __syncthreads();
  for (int o = 128; o > 0; o >>= 1) { if (t < o) { rs[t] += rs[t + o]; rq[t] += rq[t + o]; } __syncthreads(); }
  __shared__ float sm, sr;
  if (t == 0) { const float m = rs[0] / B_; const float var = rq[0] / B_ - m * m; sm = m; sr = rsqrtf(var + EPSf); }
  __syncthreads();
  glbf[(long)t * C_ + c] = f2bf(leakyf(gg[c] * (v - sm) * sr + gb[c]));
}

// ---------------------------------------------------------------------------
// K9/K10/K11: global minmax of dadj (2-pass) + normalize in place.
// ---------------------------------------------------------------------------
__global__ void k_minmax1(const float* __restrict__ d, float* __restrict__ bmin, float* __restrict__ bmax) {
  const int t = threadIdx.x;
  float lo = 3.4e38f, hi = -3.4e38f;
  for (long i = (long)blockIdx.x * TPB + t; i < BNN; i += (long)512 * TPB) {
    const float v = d[i]; lo = fminf(lo, v); hi = fmaxf(hi, v);
  }
  __shared__ float rl[TPB], rh[TPB];
  rl[t] = lo; rh[t] = hi; __syncthreads();
  for (int o = 128; o > 0; o >>= 1) { if (t < o) { rl[t] = fminf(rl[t], rl[t + o]); rh[t] = fmaxf(rh[t], rh[t + o]); } __syncthreads(); }
  if (t == 0) { bmin[blockIdx.x] = rl[0]; bmax[blockIdx.x] = rh[0]; }
}

__global__ void k_minmax2(const float* __restrict__ bmin, const float* __restrict__ bmax, float* __restrict__ dmm) {
  const int t = threadIdx.x;
  float lo = fminf(bmin[t], bmin[t + 256]);
  float hi = fmaxf(bmax[t], bmax[t + 256]);
  __shared__ float rl[TPB], rh[TPB];
  rl[t] = lo; rh[t] = hi; __syncthreads();
  for (int o = 128; o > 0; o >>= 1) { if (t < o) { rl[t] = fminf(rl[t], rl[t + o]); rh[t] = fmaxf(rh[t], rh[t + o]); } __syncthreads(); }
  if (t == 0) { dmm[0] = rl[0]; dmm[1] = 1.0f / (rh[0] - rl[0]); }
}

__global__ void k_dadjnorm(float* __restrict__ d, const float* __restrict__ dmm) {
  const long i = ((long)blockIdx.x * TPB + threadIdx.x) * 4;
  const float lo = dmm[0], inv = dmm[1];
  float4 v = *(const float4*)&d[i];
  v.x = (v.x - lo) * inv; v.y = (v.y - lo) * inv; v.z = (v.z - lo) * inv; v.w = (v.w - lo) * inv;
  *(float4*)&d[i] = v;
}

// ---------------------------------------------------------------------------
// K12: loss per batch.
// ---------------------------------------------------------------------------
__global__ void k_loss(const float* __restrict__ dadj, const float* __restrict__ sadj,
                       const float* __restrict__ out1, float* __restrict__ lossa) {
  const int b = blockIdx.x, t = threadIdx.x;
  const float* db = dadj + (long)b * NN;
  const float* o1 = out1 + b * N_;
  float p2 = 0.f;
  for (int i = t; i < NN; i += TPB) { const float d = db[i] - sadj[i]; p2 += d * d; }
  float p1 = 0.f;
  if (t < N_) {
    float acc = 0.f;
    for (int n = 0; n < N_; ++n) acc += o1[n] * db[n * N_ + t];
    const float d = o1[t] - acc * (1.0f / N_);
    p1 = d * d;
  }
  __shared__ float red[TPB];
  __shared__ float s2;
  red[t] = p2; __syncthreads();
  for (int o = 128; o > 0; o >>= 1) { if (t < o) red[t] += red[t + o]; __syncthreads(); }
  if (t == 0) s2 = red[0];
  __syncthreads();
  red[t] = p1; __syncthreads();
  for (int o = 128; o > 0; o >>= 1) { if (t < o) red[t] += red[t + o]; __syncthreads(); }
  if (t == 0) atomicAdd(lossa, sqrtf(s2) + sqrtf(red[0]));
}

// ---------------------------------------------------------------------------
// K14: final BN + leaky in place on d_out (B,C,N); writes loss scalar.
// ---------------------------------------------------------------------------
__global__ void k_final(float* __restrict__ outp, const float* __restrict__ g, const float* __restrict__ be,
                        const float* __restrict__ mu, const float* __restrict__ rstd,
                        const float* __restrict__ lossa) {
  const long i = ((long)blockIdx.x * TPB + threadIdx.x) * 4;
  const int c = (int)((i / N_) % C_);
  float4 v = *(const float4*)&outp[i];
  const float gm = g[c] * rstd[c], m = mu[c], bb = be[c];
  v.x = leakyf(gm * (v.x - m) + bb);
  v.y = leakyf(gm * (v.y - m) + bb);
  v.z = leakyf(gm * (v.z - m) + bb);
  v.w = leakyf(gm * (v.w - m) + bb);
  *(float4*)&outp[i] = v;
  if (blockIdx.x == 0 && threadIdx.x == 0) outp[BCN] = *lossa;
}

// ---------------------------------------------------------------------------
extern "C" void kernel_launch(void* const* d_in, const int* in_sizes, int n_in,
                              void* d_out, int out_size, void* d_ws, size_t ws_size,
                              hipStream_t stream) {
  const float* x    = (const float*)d_in[0];
  const float* out1 = (const float*)d_in[1];
  const float* ap   = (const float*)d_in[2];
  const float* Ws   = (const float*)d_in[3];
  const float* Wd   = (const float*)d_in[4];
  const float* Wg   = (const float*)d_in[5];
  const float* bg   = (const float*)d_in[6];
  const float* Wco  = (const float*)d_in[7];
  const float* bco  = (const float*)d_in[8];
  const float* bn_g  = (const float*)d_in[9];
  const float* bn_b  = (const float*)d_in[10];
  const float* bng_g = (const float*)d_in[11];
  const float* bng_b = (const float*)d_in[12];
  float* out = (float*)d_out;

  float* w = (float*)d_ws;
  float* sadj  = w;                    // 6400
  float* dadj  = sadj + NN;            // 1638400
  float* glb0  = dadj + BNN;           // 262144 (used as bf16 ushorts)
  float* glb1  = glb0 + B_ * C_;       // 262144
  float* glbf  = glb1 + B_ * C_;       // 262144 (used as bf16 ushorts)
  float* go    = glbf + B_ * C_;       // 20480
  float* mu1   = go + BNr;             // 1024
  float* rstd1 = mu1 + C_;             // 1024
  float* mu2   = rstd1 + C_;           // 1024
  float* rstd2 = mu2 + C_;             // 1024
  float* bmin  = rstd2 + C_;           // 512
  float* bmax  = bmin + 512;           // 512
  float* dmm   = bmax + 512;           // 2
  float* lossa = dmm + 2;              // 1
  ushort* ub   = (ushort*)(((uintptr_t)(lossa + 1) + 255) & ~(uintptr_t)255);
  ushort* xa_bf  = ub;                    // BCN bf16 (B,N,C) — reused for xt
  ushort* hT_bf  = xa_bf + BCN;           // BCN bf16 (B,C,N); later reused as x2t
  ushort* Wts    = hT_bf + BCN;           // 1M bf16 (O,C)
  ushort* Wtd    = Wts + (size_t)C_ * C_; // 1M bf16 (O,C)
  ushort* Wco2t  = Wtd + (size_t)C_ * C_; // 80K bf16 (80,1024)
  ushort* adj_bf = Wco2t + (size_t)N_ * C_; // 80x96 bf16 prepadded
  ushort* x2t_bf = hT_bf;                 // alias: hT dead after k_x2
  // bf16 aliases in regions dead at time of use:
  ushort* Wg_bf   = (ushort*)dadj;                      // 1M ushorts; dadj written later
  ushort* Wco1t   = (ushort*)dadj + (size_t)C_ * C_;    // 80K ushorts, same region
  ushort* glb0_bf = (ushort*)glb0;                      // glb0 only ever bf16
  ushort* glbf_bf = (ushort*)glbf;                      // glbf only ever bf16

  // ---- prep ----
  k_prep_adj<<<1, TPB, 0, stream>>>(ap, sadj, adj_bf, lossa);
  k_w_bf_t<<<dim3(32, 32), TPB, 0, stream>>>(Ws, Wts);
  k_w_bf_t<<<dim3(32, 32), TPB, 0, stream>>>(Wd, Wtd);
  k_wco_bf<<<(N_ * 2 * C_) / (4 * TPB), TPB, 0, stream>>>(Wco, Wco1t, Wco2t);
  k_cvt_bf<<<(C_ * C_) / (4 * TPB), TPB, 0, stream>>>(Wg, Wg_bf);
  k_zero_go<<<BNr / (4 * TPB), TPB, 0, stream>>>(go);

  // ---- static GCN ----
  k_fold_mfma<<<B_ * 8, TPB, 0, stream>>>(x, adj_bf, xa_bf, 0);
  k_gemm_mfma<<<dim3(C_ / 128, BNr / 128), TPB, 0, stream>>>(xa_bf, Wts, hT_bf, 1);
  k_bn_stats_bf<<<C_, TPB, 0, stream>>>(hT_bf, mu1, rstd1);
  k_x2<<<(int)(BCN / (4 * TPB)), TPB, 0, stream>>>(x, hT_bf, bn_g, bn_b, mu1, rstd1, out);

  // ---- dynamic graph construction ----
  k_x2t<<<(B_ * C_) / 64, TPB, 0, stream>>>(out, x2t_bf);
  k_glb0<<<(B_ * C_ * 64) / TPB, TPB, 0, stream>>>(out, glb0_bf);
  k_glb_mfma<<<dim3(C_ / 64, B_ / 64), TPB, 0, stream>>>(glb0_bf, Wg_bf, bg, glb1);
  k_bng<<<C_, TPB, 0, stream>>>(glb1, bng_g, bng_b, glbf_bf);
  k_go_mfma<<<dim3(8, B_ / 128), TPB, 0, stream>>>(glbf_bf, Wco1t, go);
  k_dadj_mfma<<<BNr / 128, TPB, 0, stream>>>(x2t_bf, Wco2t, go, bco, dadj);
  k_minmax1<<<512, TPB, 0, stream>>>(dadj, bmin, bmax);
  k_minmax2<<<1, TPB, 0, stream>>>(bmin, bmax, dmm);
  k_dadjnorm<<<BNN / (4 * TPB), TPB, 0, stream>>>(dadj, dmm);

  // ---- adjacency loss ----
  k_loss<<<B_, TPB, 0, stream>>>(dadj, sadj, out1, lossa);

  // ---- dynamic GCN ----
  k_fold_mfma<<<B_ * 8, TPB, 0, stream>>>(out, dadj, xa_bf, 1);   // tadj folded in
  k_gemm_mfma<<<dim3(C_ / 128, BNr / 128), TPB, 0, stream>>>(xa_bf, Wtd, out, 0);
  k_bn_stats<<<C_, TPB, 0, stream>>>(out, mu2, rstd2);
  k_final<<<(int)(BCN / (4 * TPB)), TPB, 0, stream>>>(out, bn_g, bn_b, mu2, rstd2, lossa);
}